// Round 1
// baseline (321.328 us; speedup 1.0000x reference)
//
#include <hip/hip_runtime.h>
#include <stdint.h>

#define MB (1ull << 20)

typedef __attribute__((ext_vector_type(8))) short bf16x8;
typedef __attribute__((ext_vector_type(8))) unsigned short u16x8;
typedef __attribute__((ext_vector_type(4))) float f32x4;

static __device__ __forceinline__ unsigned short f2bf(float f) {
    unsigned u = __builtin_bit_cast(unsigned, f);
    u += 0x7fffu + ((u >> 16) & 1u);   // round-to-nearest-even
    return (unsigned short)(u >> 16);
}
static __device__ __forceinline__ float bf2f(unsigned short h) {
    return __builtin_bit_cast(float, ((unsigned)h) << 16);
}

// ---------------- prep: x f32 -> bf16 ----------------
__global__ __launch_bounds__(256) void cvt_x_kernel(const float* __restrict__ x,
                                                    unsigned short* __restrict__ xb, int n8) {
    int i = blockIdx.x * blockDim.x + threadIdx.x;
    if (i >= n8) return;
    const float4* px = (const float4*)x + (size_t)i * 2;
    float4 a = px[0], b = px[1];
    u16x8 o;
    o[0] = f2bf(a.x); o[1] = f2bf(a.y); o[2] = f2bf(a.z); o[3] = f2bf(a.w);
    o[4] = f2bf(b.x); o[5] = f2bf(b.y); o[6] = f2bf(b.z); o[7] = f2bf(b.w);
    ((u16x8*)xb)[i] = o;
}

// ---------------- prep: Wt[n][k] = concat(ek,wk)^T as bf16, n in [0,2048) ----------------
__global__ __launch_bounds__(256) void cvt_w_kernel(const float* __restrict__ ek,
                                                    const float* __restrict__ wk,
                                                    unsigned short* __restrict__ wt) {
    int t = blockIdx.x * blockDim.x + threadIdx.x;  // 0 .. 2048*128-1
    int n = t >> 7;
    int kb = (t & 127) * 8;
    const float* src = (n < 1024) ? ek : wk;
    int col = n & 1023;
    u16x8 o;
#pragma unroll
    for (int j = 0; j < 8; ++j) o[j] = f2bf(src[(size_t)(kb + j) * 1024 + col]);
    ((u16x8*)wt)[t] = o;
}

// ---------------- fused dual-gate GEMM: [16384,1024] x [1024,2048] ----------------
// Epilogue stores a = 1-sigmoid(z) (cols<1024) or w*x = sigmoid(z)*x (cols>=1024).
template <bool HALFG>
__global__ __launch_bounds__(256) void gate_gemm(const unsigned short* __restrict__ Xb,
                                                 const unsigned short* __restrict__ Wt,
                                                 const float* __restrict__ eb,
                                                 const float* __restrict__ wb,
                                                 const float* __restrict__ xf,
                                                 void* __restrict__ AgV, void* __restrict__ WXgV) {
    __shared__ alignas(16) unsigned short As[128 * 32];  // [m][k]
    __shared__ alignas(16) unsigned short Bs[128 * 32];  // [n][k]
    const int tid = threadIdx.x;
    const int lane = tid & 63;
    const int w = tid >> 6;
    const int wr = w >> 1, wc = w & 1;
    const int m0 = blockIdx.x * 128;
    const int n0 = blockIdx.y * 128;
    const int colq = lane & 15, rowq = lane >> 4;

    const int smi = tid >> 2;         // staging row (0..63)
    const int skk = (tid & 3) * 8;    // staging k offset

    f32x4 acc[4][4] = {};

    for (int k0 = 0; k0 < 1024; k0 += 32) {
        const unsigned short* sA0 = Xb + (size_t)(m0 + smi) * 1024 + k0 + skk;
        const unsigned short* sA1 = Xb + (size_t)(m0 + 64 + smi) * 1024 + k0 + skk;
        const unsigned short* sB0 = Wt + (size_t)(n0 + smi) * 1024 + k0 + skk;
        const unsigned short* sB1 = Wt + (size_t)(n0 + 64 + smi) * 1024 + k0 + skk;
        __builtin_amdgcn_global_load_lds((const __attribute__((address_space(1))) void*)sA0,
                                         (__attribute__((address_space(3))) void*)&As[tid * 8], 16, 0, 0);
        __builtin_amdgcn_global_load_lds((const __attribute__((address_space(1))) void*)sA1,
                                         (__attribute__((address_space(3))) void*)&As[2048 + tid * 8], 16, 0, 0);
        __builtin_amdgcn_global_load_lds((const __attribute__((address_space(1))) void*)sB0,
                                         (__attribute__((address_space(3))) void*)&Bs[tid * 8], 16, 0, 0);
        __builtin_amdgcn_global_load_lds((const __attribute__((address_space(1))) void*)sB1,
                                         (__attribute__((address_space(3))) void*)&Bs[2048 + tid * 8], 16, 0, 0);
        asm volatile("s_waitcnt vmcnt(0)" ::: "memory");
        __syncthreads();

        bf16x8 af[4], bfr[4];
#pragma unroll
        for (int f = 0; f < 4; ++f)
            af[f] = *(const bf16x8*)&As[(wr * 64 + f * 16 + colq) * 32 + rowq * 8];
#pragma unroll
        for (int f = 0; f < 4; ++f)
            bfr[f] = *(const bf16x8*)&Bs[(wc * 64 + f * 16 + colq) * 32 + rowq * 8];
#pragma unroll
        for (int i2 = 0; i2 < 4; ++i2)
#pragma unroll
            for (int j2 = 0; j2 < 4; ++j2)
                acc[i2][j2] = __builtin_amdgcn_mfma_f32_16x16x32_bf16(af[i2], bfr[j2], acc[i2][j2], 0, 0, 0);
        __syncthreads();
    }

    const bool isE = (n0 < 1024);
    const float* bias = isE ? eb : wb;
    const int nb = isE ? n0 : (n0 - 1024);
    void* outp = isE ? AgV : WXgV;
#pragma unroll
    for (int i2 = 0; i2 < 4; ++i2) {
        const int gmb = m0 + wr * 64 + i2 * 16 + rowq * 4;
#pragma unroll
        for (int j2 = 0; j2 < 4; ++j2) {
            const int gn = nb + wc * 64 + j2 * 16 + colq;
            const float bv = bias[gn];
#pragma unroll
            for (int r = 0; r < 4; ++r) {
                const size_t oidx = (size_t)(gmb + r) * 1024 + gn;
                const float z = acc[i2][j2][r] + bv;
                float val;
                if (isE) {
                    val = 1.0f / (1.0f + __expf(z));            // a = 1 - sigmoid(z)
                } else {
                    val = (1.0f / (1.0f + __expf(-z))) * xf[oidx];  // w * x
                }
                if constexpr (HALFG) ((unsigned short*)outp)[oidx] = f2bf(val);
                else                 ((float*)outp)[oidx] = val;
            }
        }
    }
}

// ---------------- scan phase 1: per-chunk summaries (Lc=64, NC=64) ----------------
template <bool H>
__global__ __launch_bounds__(256) void scan_phase1(const void* __restrict__ Ag,
                                                   const void* __restrict__ WXg,
                                                   float* __restrict__ Asum, float* __restrict__ Bsum) {
    const int c = blockIdx.x, b = blockIdx.y, dz = blockIdx.z;
    const int d = dz * 256 + threadIdx.x;
    size_t base = ((size_t)(b * 4096 + c * 64)) * 1024 + d;
    float ap = 1.0f, s = 0.0f;
#pragma unroll 8
    for (int i = 0; i < 64; ++i) {
        float a, wx;
        if constexpr (H) {
            a = bf2f(((const unsigned short*)Ag)[base]);
            wx = bf2f(((const unsigned short*)WXg)[base]);
        } else {
            a = ((const float*)Ag)[base];
            wx = ((const float*)WXg)[base];
        }
        s = fmaf(s, a, wx);
        ap *= a;
        base += 1024;
    }
    const size_t so = ((size_t)(b * 64 + c)) * 1024 + d;
    Asum[so] = ap;
    Bsum[so] = s;
}

// ---------------- scan phase 2: combine chunk summaries -> chunk entry states ----------------
__global__ __launch_bounds__(256) void scan_phase2(const float* __restrict__ st,
                                                   const float* __restrict__ Asum,
                                                   const float* __restrict__ Bsum,
                                                   float* __restrict__ Sin) {
    const int t = blockIdx.x * 256 + threadIdx.x;  // 0..4095 = b*1024 + d
    const int b = t >> 10, d = t & 1023;
    float s = st[t];
    size_t idx = (size_t)(b * 64) * 1024 + d;
#pragma unroll 8
    for (int c = 0; c < 64; ++c) {
        Sin[idx] = s;
        s = fmaf(s, Asum[idx], Bsum[idx]);
        idx += 1024;
    }
}

// ---------------- scan phase 3: recompute with entry state, write out ----------------
template <bool H>
__global__ __launch_bounds__(256) void scan_phase3(const void* __restrict__ Ag,
                                                   const void* __restrict__ WXg,
                                                   const float* __restrict__ Sin,
                                                   float* __restrict__ out) {
    const int c = blockIdx.x, b = blockIdx.y, dz = blockIdx.z;
    const int d = dz * 256 + threadIdx.x;
    size_t base = ((size_t)(b * 4096 + c * 64)) * 1024 + d;
    float s = Sin[((size_t)(b * 64 + c)) * 1024 + d];
#pragma unroll 4
    for (int i = 0; i < 64; ++i) {
        float a, wx;
        if constexpr (H) {
            a = bf2f(((const unsigned short*)Ag)[base]);
            wx = bf2f(((const unsigned short*)WXg)[base]);
        } else {
            a = ((const float*)Ag)[base];
            wx = ((const float*)WXg)[base];
        }
        s = fmaf(s, a, wx);
        out[base] = s;
        base += 1024;
    }
}

extern "C" void kernel_launch(void* const* d_in, const int* in_sizes, int n_in,
                              void* d_out, int out_size, void* d_ws, size_t ws_size,
                              hipStream_t stream) {
    const float* x  = (const float*)d_in[0];
    const float* st = (const float*)d_in[1];
    const float* ek = (const float*)d_in[2];
    const float* eb = (const float*)d_in[3];
    const float* wk = (const float*)d_in[4];
    const float* wb = (const float*)d_in[5];
    float* out = (float*)d_out;
    char* ws = (char*)d_ws;

    unsigned short* xb = (unsigned short*)ws;            // 32 MB bf16 x
    unsigned short* wt = (unsigned short*)(ws + 32 * MB); // 4 MB bf16 Wt
    const bool halfg = ws_size < 167 * MB;               // f32 gates need 167 MB total
    char* p = ws + 36 * MB;
    const size_t gbytes = halfg ? 32 * MB : 64 * MB;
    void* Ag = (void*)p;
    void* WXg = (void*)(p + gbytes);
    float* Asum = (float*)(p + 2 * gbytes);
    float* Bsum = Asum + (size_t)4 * 64 * 1024;
    float* Sin  = Bsum + (size_t)4 * 64 * 1024;

    cvt_x_kernel<<<8192, 256, 0, stream>>>(x, xb, 2097152);
    cvt_w_kernel<<<1024, 256, 0, stream>>>(ek, wk, wt);

    dim3 ggrid(128, 16);
    dim3 sgrid(64, 4, 4);
    if (halfg) {
        gate_gemm<true><<<ggrid, 256, 0, stream>>>(xb, wt, eb, wb, x, Ag, WXg);
        scan_phase1<true><<<sgrid, 256, 0, stream>>>(Ag, WXg, Asum, Bsum);
        scan_phase2<<<16, 256, 0, stream>>>(st, Asum, Bsum, Sin);
        scan_phase3<true><<<sgrid, 256, 0, stream>>>(Ag, WXg, Sin, out);
    } else {
        gate_gemm<false><<<ggrid, 256, 0, stream>>>(xb, wt, eb, wb, x, Ag, WXg);
        scan_phase1<false><<<sgrid, 256, 0, stream>>>(Ag, WXg, Asum, Bsum);
        scan_phase2<<<16, 256, 0, stream>>>(st, Asum, Bsum, Sin);
        scan_phase3<false><<<sgrid, 256, 0, stream>>>(Ag, WXg, Sin, out);
    }
}